// Round 4
// baseline (188.823 us; speedup 1.0000x reference)
//
#include <hip/hip_runtime.h>
#include <hip/hip_cooperative_groups.h>

namespace cg = cooperative_groups;

#define Bn 4
#define Ln 512
#define Hn 768
#define Sn 100
#define Rn 100
#define En 128
#define TEn 8
#define TRn 6
#define NEGF (-1e20f)
#define W 8
#define NBLK (Ln / W)      // 64
#define H4 (Hn / 4)        // 192
#define E4 (En / 4)        // 32
#define NTHR 192

__device__ __forceinline__ float4 fmax4(float4 a, float4 b) {
    return make_float4(fmaxf(a.x, b.x), fmaxf(a.y, b.y),
                       fmaxf(a.z, b.z), fmaxf(a.w, b.w));
}

// 192-thread (3-wave) block reduce: per-thread acc[NT] -> out row (+bias)
template <int NT>
__device__ __forceinline__ void block_reduce_store(float* acc,
                                                   const float* __restrict__ bias,
                                                   float* __restrict__ out_row,
                                                   int tid) {
    #pragma unroll
    for (int t = 0; t < NT; ++t)
        #pragma unroll
        for (int off = 32; off > 0; off >>= 1)
            acc[t] += __shfl_down(acc[t], off, 64);
    __shared__ float red[3][NT];
    int wave = tid >> 6, lane = tid & 63;
    if (lane == 0) {
        #pragma unroll
        for (int t = 0; t < NT; ++t) red[wave][t] = acc[t];
    }
    __syncthreads();
    if (tid < NT) {
        float s = bias[tid];
        #pragma unroll
        for (int w = 0; w < 3; ++w) s += red[w][tid];
        out_row[tid] = s;
    }
}

// ---------------------------------------------------------------------------
// Single cooperative kernel, grid = B*(S+R) = 800 blocks x 192 threads.
// Phase 0: mask compaction (all blocks) + bmax precompute (blocks 0..255).
// Phase 1: masked max (bmax blocks + edge rows) + inline entity logits.
// Phase 2: relation logits (blocks 0..399).
// ---------------------------------------------------------------------------
__global__ void __launch_bounds__(NTHR)
fused_kernel(const float* __restrict__ hid,
             const int* __restrict__ ent_mask,
             const int* __restrict__ rel_mask,
             const int* __restrict__ samp_mask,
             const int* __restrict__ relations,
             const float* __restrict__ size_emb,
             const float* __restrict__ span_w,
             const float* __restrict__ span_b,
             const float* __restrict__ rel_w,
             const float* __restrict__ rel_b,
             float* __restrict__ entity,
             float* __restrict__ relctx,
             float* __restrict__ bmax,
             int* __restrict__ entcnt,
             float* __restrict__ out_ent,
             float* __restrict__ out_rel) {
    cg::grid_group grid = cg::this_grid();
    int blk = blockIdx.x;                  // 0 .. B*(S+R)-1
    int tid = threadIdx.x;                 // 0 .. 191
    int b = blk / (Sn + Rn);
    int idx = blk % (Sn + Rn);
    bool is_rel = idx >= Sn;
    int span = is_rel ? idx - Sn : idx;

    __shared__ int rows[Ln];
    __shared__ int blks[NBLK];
    __shared__ int nrows_s, nblks_s, cnt_s;

    bool zero_out = is_rel && (samp_mask[b * Rn + span] == 1);

    if (tid == 0) { nrows_s = 0; nblks_s = 0; cnt_s = 0; }
    __syncthreads();

    // ---- phase 0a: mask compaction (wave 0 only; skip for zeroed rel spans)
    if (!zero_out && tid < NBLK) {
        const int* mask = is_rel ? rel_mask + ((size_t)b * Rn + span) * Ln
                                 : ent_mask + ((size_t)b * Sn + span) * Ln;
        const int4* m4 = (const int4*)(mask + tid * W);
        int4 a = m4[0], c = m4[1];
        int mm[8] = {a.x, a.y, a.z, a.w, c.x, c.y, c.z, c.w};
        int s = 0;
        #pragma unroll
        for (int r = 0; r < 8; ++r) s += (mm[r] != 0);
        if (s == 8) {
            blks[atomicAdd(&nblks_s, 1)] = tid;
        } else if (s > 0) {
            #pragma unroll
            for (int r = 0; r < 8; ++r)
                if (mm[r] != 0) rows[atomicAdd(&nrows_s, 1)] = tid * W + r;
        }
        int cnt = s;
        #pragma unroll
        for (int off = 32; off > 0; off >>= 1) cnt += __shfl_down(cnt, off, 64);
        if (tid == 0) {
            cnt_s = cnt;
            if (!is_rel) entcnt[b * Sn + span] = cnt;
        }
    }

    // ---- phase 0b: blocks 0..B*NBLK-1 compute 8-row block maxes
    if (blk < Bn * NBLK) {
        int bb = blk / NBLK, j = blk % NBLK;
        const float4* src = (const float4*)(hid + ((size_t)bb * Ln + j * W) * Hn);
        float4 m0 = src[tid];
        #pragma unroll
        for (int r = 1; r < W; ++r)
            m0 = fmax4(m0, src[(size_t)r * H4 + tid]);
        ((float4*)(bmax + (size_t)blk * Hn))[tid] = m0;
    }

    grid.sync();

    // ---- phase 1: masked max + inline entity logit
    int nrows = nrows_s, nblks = nblks_s, cnt = cnt_s;
    const float4* hb4 = (const float4*)(hid + (size_t)b * Ln * Hn);
    const float4* bm4 = (const float4*)(bmax + (size_t)b * NBLK * Hn);

    float4 m = make_float4(NEGF, NEGF, NEGF, NEGF);
    if (!zero_out) {
        int i = 0;
        for (; i + 2 <= nblks; i += 2) {
            float4 v0 = bm4[(size_t)blks[i] * H4 + tid];
            float4 v1 = bm4[(size_t)blks[i + 1] * H4 + tid];
            m = fmax4(m, fmax4(v0, v1));
        }
        for (; i < nblks; ++i)
            m = fmax4(m, bm4[(size_t)blks[i] * H4 + tid]);
        i = 0;
        for (; i + 2 <= nrows; i += 2) {
            float4 v0 = hb4[(size_t)rows[i] * H4 + tid];
            float4 v1 = hb4[(size_t)rows[i + 1] * H4 + tid];
            m = fmax4(m, fmax4(v0, v1));
        }
        for (; i < nrows; ++i)
            m = fmax4(m, hb4[(size_t)rows[i] * H4 + tid]);
    } else {
        m = make_float4(0.f, 0.f, 0.f, 0.f);
    }

    float4* out4 = (float4*)(is_rel ? relctx + ((size_t)b * Rn + span) * Hn
                                    : entity + ((size_t)b * Sn + span) * Hn);
    out4[tid] = m;

    if (!is_rel) {
        // entity logit: [entity | ctx | size] @ span_w + span_b
        float acc[TEn];
        #pragma unroll
        for (int t = 0; t < TEn; ++t) acc[t] = 0.0f;

        const float* vv = &m.x;                       // own entity dims 4t..4t+3
        #pragma unroll
        for (int j = 0; j < 4; ++j) {
            const float4* w4 = (const float4*)(span_w + (size_t)(4 * tid + j) * TEn);
            float4 wa = w4[0], wb = w4[1];
            acc[0] += vv[j] * wa.x; acc[1] += vv[j] * wa.y;
            acc[2] += vv[j] * wa.z; acc[3] += vv[j] * wa.w;
            acc[4] += vv[j] * wb.x; acc[5] += vv[j] * wb.y;
            acc[6] += vv[j] * wb.z; acc[7] += vv[j] * wb.w;
        }
        float4 c = ((const float4*)(hid + (size_t)b * Ln * Hn))[tid];  // ctx row 0
        const float* cc = &c.x;
        #pragma unroll
        for (int j = 0; j < 4; ++j) {
            const float4* w4 = (const float4*)(span_w + (size_t)(Hn + 4 * tid + j) * TEn);
            float4 wa = w4[0], wb = w4[1];
            acc[0] += cc[j] * wa.x; acc[1] += cc[j] * wa.y;
            acc[2] += cc[j] * wa.z; acc[3] += cc[j] * wa.w;
            acc[4] += cc[j] * wb.x; acc[5] += cc[j] * wb.y;
            acc[6] += cc[j] * wb.z; acc[7] += cc[j] * wb.w;
        }
        if (tid < E4) {
            float4 sv = ((const float4*)(size_emb + (size_t)cnt * En))[tid];
            const float* ss = &sv.x;
            #pragma unroll
            for (int j = 0; j < 4; ++j) {
                const float4* w4 = (const float4*)(span_w + (size_t)(2 * Hn + 4 * tid + j) * TEn);
                float4 wa = w4[0], wb = w4[1];
                acc[0] += ss[j] * wa.x; acc[1] += ss[j] * wa.y;
                acc[2] += ss[j] * wa.z; acc[3] += ss[j] * wa.w;
                acc[4] += ss[j] * wb.x; acc[5] += ss[j] * wb.y;
                acc[6] += ss[j] * wb.z; acc[7] += ss[j] * wb.w;
            }
        }
        block_reduce_store<TEn>(acc, span_b,
                                out_ent + (size_t)(b * Sn + span) * TEn, tid);
    }

    grid.sync();

    // ---- phase 2: relation logits on blocks 0..B*R-1
    if (blk < Bn * Rn) {
        int rb = blk / Rn;                            // batch
        int a0 = relations[blk * 2 + 0];
        int a1 = relations[blk * 2 + 1];
        const float4* ctx4 = (const float4*)(relctx + (size_t)blk * Hn);
        const float4* e04  = (const float4*)(entity + ((size_t)rb * Sn + a0) * Hn);
        const float4* e14  = (const float4*)(entity + ((size_t)rb * Sn + a1) * Hn);
        const float4* s04  = (const float4*)(size_emb + (size_t)entcnt[rb * Sn + a0] * En);
        const float4* s14  = (const float4*)(size_emb + (size_t)entcnt[rb * Sn + a1] * En);

        float acc[TRn];
        #pragma unroll
        for (int t = 0; t < TRn; ++t) acc[t] = 0.0f;

        const int K4 = 3 * H4 + 2 * E4;               // 640
        for (int k4 = tid; k4 < K4; k4 += NTHR) {
            float4 v;
            if (k4 < H4)               v = ctx4[k4];
            else if (k4 < 2 * H4)      v = e04[k4 - H4];
            else if (k4 < 3 * H4)      v = e14[k4 - 2 * H4];
            else if (k4 < 3 * H4 + E4) v = s04[k4 - 3 * H4];
            else                       v = s14[k4 - 3 * H4 - E4];
            int k = k4 * 4;
            const float* vp = &v.x;
            #pragma unroll
            for (int j = 0; j < 4; ++j) {
                const float2* wr = (const float2*)(rel_w + (size_t)(k + j) * TRn);
                float2 w0 = wr[0], w1 = wr[1], w2 = wr[2];
                acc[0] += vp[j] * w0.x; acc[1] += vp[j] * w0.y;
                acc[2] += vp[j] * w1.x; acc[3] += vp[j] * w1.y;
                acc[4] += vp[j] * w2.x; acc[5] += vp[j] * w2.y;
            }
        }
        block_reduce_store<TRn>(acc, rel_b, out_rel + (size_t)blk * TRn, tid);
    }
}

extern "C" void kernel_launch(void* const* d_in, const int* in_sizes, int n_in,
                              void* d_out, int out_size, void* d_ws, size_t ws_size,
                              hipStream_t stream) {
    const float* hid       = (const float*)d_in[0];   // (B,L,H)
    const int*   ent_mask  = (const int*)d_in[1];     // (B,S,L)
    const int*   relations = (const int*)d_in[2];     // (B,R,2)
    const int*   rel_mask  = (const int*)d_in[3];     // (B,R,L)
    const int*   samp_mask = (const int*)d_in[4];     // (B,R)
    const float* size_emb  = (const float*)d_in[5];   // (100,E)
    const float* span_w    = (const float*)d_in[6];   // (2H+E, TE)
    const float* span_b    = (const float*)d_in[7];   // (TE,)
    const float* rel_w     = (const float*)d_in[8];   // (3H+2E, TR)
    const float* rel_b     = (const float*)d_in[9];   // (TR,)

    float* out = (float*)d_out;
    float* out_ent = out;                       // (B,S,TE)
    float* out_rel = out + Bn * Sn * TEn;       // (B,R,TR)

    char* ws = (char*)d_ws;
    float* entity = (float*)ws;                               // B*S*H
    float* relctx = entity + (size_t)Bn * Sn * Hn;            // B*R*H
    float* bmax   = relctx + (size_t)Bn * Rn * Hn;            // B*NBLK*H
    int*   entcnt = (int*)(bmax + (size_t)Bn * NBLK * Hn);    // B*S

    void* args[] = {
        (void*)&hid, (void*)&ent_mask, (void*)&rel_mask, (void*)&samp_mask,
        (void*)&relations, (void*)&size_emb, (void*)&span_w, (void*)&span_b,
        (void*)&rel_w, (void*)&rel_b, (void*)&entity, (void*)&relctx,
        (void*)&bmax, (void*)&entcnt, (void*)&out_ent, (void*)&out_rel
    };
    hipLaunchCooperativeKernel((void*)fused_kernel,
                               dim3(Bn * (Sn + Rn)), dim3(NTHR),
                               args, 0, stream);
}

// Round 5
// 26.223 us; speedup vs baseline: 7.2007x; 7.2007x over previous
//
#include <hip/hip_runtime.h>

#define Bn 4
#define Ln 512
#define Hn 768
#define Sn 100
#define Rn 100
#define En 128
#define TEn 8
#define TRn 6
#define NEGF (-1e20f)
#define H4 (Hn / 4)        // 192
#define E4 (En / 4)        // 32

__device__ __forceinline__ float4 fmax4(float4 a, float4 b) {
    return make_float4(fmaxf(a.x, b.x), fmaxf(a.y, b.y),
                       fmaxf(a.z, b.z), fmaxf(a.w, b.w));
}

// ---------------------------------------------------------------------------
// K_A: one 192-thread block per span (b, entity s | relation r).
//   - every wave independently scans the mask (2KB) -> start/end/count
//     (span masks are contiguous runs by construction)
//   - stream rows [start,end) with float4/thread, 4 rows in flight
//   - write entity/relctx; entity blocks fuse the entity logit inline
// ---------------------------------------------------------------------------
__global__ void __launch_bounds__(192)
span_kernel(const float* __restrict__ hid,
            const int* __restrict__ ent_mask,
            const int* __restrict__ rel_mask,
            const int* __restrict__ samp_mask,
            const float* __restrict__ size_emb,
            const float* __restrict__ span_w,
            const float* __restrict__ span_b,
            float* __restrict__ entity,
            float* __restrict__ relctx,
            int* __restrict__ entcnt,
            float* __restrict__ out_ent) {
    int blk = blockIdx.x;                  // 0 .. B*(S+R)-1
    int tid = threadIdx.x;                 // 0 .. 191
    int lane = tid & 63;
    int b = blk / (Sn + Rn);
    int idx = blk % (Sn + Rn);
    bool is_rel = idx >= Sn;
    int span = is_rel ? idx - Sn : idx;

    float4* out4 = (float4*)(is_rel ? relctx + ((size_t)b * Rn + span) * Hn
                                    : entity + ((size_t)b * Sn + span) * Hn) + tid;

    bool zero_out = is_rel && (samp_mask[b * Rn + span] == 1);
    if (zero_out) {
        *out4 = make_float4(0.f, 0.f, 0.f, 0.f);
        return;
    }

    // ---- mask scan: each wave does it redundantly (no barriers needed)
    const int* mask = is_rel ? rel_mask + ((size_t)b * Rn + span) * Ln
                             : ent_mask + ((size_t)b * Sn + span) * Ln;
    const int4* m4 = (const int4*)(mask + lane * 8);
    int4 ma = m4[0], mb = m4[1];
    int mm[8] = {ma.x, ma.y, ma.z, ma.w, mb.x, mb.y, mb.z, mb.w};
    int cnt = 0, first = 0x7fffffff, last = -1;
    #pragma unroll
    for (int r = 0; r < 8; ++r) {
        if (mm[r] != 0) {
            int row = lane * 8 + r;
            ++cnt;
            first = min(first, row);
            last = max(last, row);
        }
    }
    #pragma unroll
    for (int off = 1; off < 64; off <<= 1) {
        cnt += __shfl_xor(cnt, off, 64);
        first = min(first, __shfl_xor(first, off, 64));
        last = max(last, __shfl_xor(last, off, 64));
    }
    int start = first, end = last + 1;     // contiguous run

    // ---- stream rows, 4 in flight
    const float4* hb4 = (const float4*)(hid + (size_t)b * Ln * Hn) + tid;
    float4 m = make_float4(NEGF, NEGF, NEGF, NEGF);
    int r = start;
    for (; r + 4 <= end; r += 4) {
        float4 v0 = hb4[(size_t)(r + 0) * H4];
        float4 v1 = hb4[(size_t)(r + 1) * H4];
        float4 v2 = hb4[(size_t)(r + 2) * H4];
        float4 v3 = hb4[(size_t)(r + 3) * H4];
        m = fmax4(m, fmax4(fmax4(v0, v1), fmax4(v2, v3)));
    }
    for (; r < end; ++r)
        m = fmax4(m, hb4[(size_t)r * H4]);

    *out4 = m;

    if (is_rel) return;
    if (tid == 0) entcnt[b * Sn + span] = cnt;

    // ---- fused entity logit: [entity | ctx | size] @ span_w + span_b
    float acc[TEn];
    #pragma unroll
    for (int t = 0; t < TEn; ++t) acc[t] = 0.0f;

    const float* vv = &m.x;                // own entity dims 4*tid..4*tid+3
    #pragma unroll
    for (int j = 0; j < 4; ++j) {
        const float4* w4 = (const float4*)(span_w + (size_t)(4 * tid + j) * TEn);
        float4 wa = w4[0], wb = w4[1];
        acc[0] += vv[j] * wa.x; acc[1] += vv[j] * wa.y;
        acc[2] += vv[j] * wa.z; acc[3] += vv[j] * wa.w;
        acc[4] += vv[j] * wb.x; acc[5] += vv[j] * wb.y;
        acc[6] += vv[j] * wb.z; acc[7] += vv[j] * wb.w;
    }
    float4 c = ((const float4*)(hid + (size_t)b * Ln * Hn))[tid];   // ctx row 0
    const float* cc = &c.x;
    #pragma unroll
    for (int j = 0; j < 4; ++j) {
        const float4* w4 = (const float4*)(span_w + (size_t)(Hn + 4 * tid + j) * TEn);
        float4 wa = w4[0], wb = w4[1];
        acc[0] += cc[j] * wa.x; acc[1] += cc[j] * wa.y;
        acc[2] += cc[j] * wa.z; acc[3] += cc[j] * wa.w;
        acc[4] += cc[j] * wb.x; acc[5] += cc[j] * wb.y;
        acc[6] += cc[j] * wb.z; acc[7] += cc[j] * wb.w;
    }
    if (tid < E4) {
        float4 sv = ((const float4*)(size_emb + (size_t)cnt * En))[tid];
        const float* ss = &sv.x;
        #pragma unroll
        for (int j = 0; j < 4; ++j) {
            const float4* w4 = (const float4*)(span_w + (size_t)(2 * Hn + 4 * tid + j) * TEn);
            float4 wa = w4[0], wb = w4[1];
            acc[0] += ss[j] * wa.x; acc[1] += ss[j] * wa.y;
            acc[2] += ss[j] * wa.z; acc[3] += ss[j] * wa.w;
            acc[4] += ss[j] * wb.x; acc[5] += ss[j] * wb.y;
            acc[6] += ss[j] * wb.z; acc[7] += ss[j] * wb.w;
        }
    }

    // block reduce (3 waves) + store
    #pragma unroll
    for (int t = 0; t < TEn; ++t)
        #pragma unroll
        for (int off = 32; off > 0; off >>= 1)
            acc[t] += __shfl_down(acc[t], off, 64);
    __shared__ float red[3][TEn];
    int wave = tid >> 6;
    if (lane == 0) {
        #pragma unroll
        for (int t = 0; t < TEn; ++t) red[wave][t] = acc[t];
    }
    __syncthreads();
    if (tid < TEn) {
        float s = span_b[tid];
        #pragma unroll
        for (int w = 0; w < 3; ++w) s += red[w][tid];
        out_ent[(size_t)(b * Sn + span) * TEn + tid] = s;
    }
}

// ---------------------------------------------------------------------------
// K_B: relation logits. One 256-thread block per (b,r). K = 3H + 2E = 2560.
// ---------------------------------------------------------------------------
__global__ void __launch_bounds__(256)
rel_logit_kernel(const float* __restrict__ entity,
                 const float* __restrict__ relctx,
                 const int* __restrict__ relations,
                 const int* __restrict__ entcnt,
                 const float* __restrict__ size_emb,
                 const float* __restrict__ rel_w,
                 const float* __restrict__ rel_b,
                 float* __restrict__ out_rel) {
    int blk = blockIdx.x;                  // b*R + r
    int b = blk / Rn;
    int tid = threadIdx.x;
    int a0 = relations[blk * 2 + 0];
    int a1 = relations[blk * 2 + 1];
    const float4* ctx4 = (const float4*)(relctx + (size_t)blk * Hn);
    const float4* e04  = (const float4*)(entity + ((size_t)b * Sn + a0) * Hn);
    const float4* e14  = (const float4*)(entity + ((size_t)b * Sn + a1) * Hn);
    const float4* s04  = (const float4*)(size_emb + (size_t)entcnt[b * Sn + a0] * En);
    const float4* s14  = (const float4*)(size_emb + (size_t)entcnt[b * Sn + a1] * En);

    float acc[TRn];
    #pragma unroll
    for (int t = 0; t < TRn; ++t) acc[t] = 0.0f;

    const int K4 = 3 * H4 + 2 * E4;        // 640
    for (int k4 = tid; k4 < K4; k4 += 256) {
        float4 v;
        if (k4 < H4)               v = ctx4[k4];
        else if (k4 < 2 * H4)      v = e04[k4 - H4];
        else if (k4 < 3 * H4)      v = e14[k4 - 2 * H4];
        else if (k4 < 3 * H4 + E4) v = s04[k4 - 3 * H4];
        else                       v = s14[k4 - 3 * H4 - E4];
        int k = k4 * 4;
        const float* vp = &v.x;
        #pragma unroll
        for (int j = 0; j < 4; ++j) {
            const float2* wr = (const float2*)(rel_w + (size_t)(k + j) * TRn);
            float2 w0 = wr[0], w1 = wr[1], w2 = wr[2];
            acc[0] += vp[j] * w0.x; acc[1] += vp[j] * w0.y;
            acc[2] += vp[j] * w1.x; acc[3] += vp[j] * w1.y;
            acc[4] += vp[j] * w2.x; acc[5] += vp[j] * w2.y;
        }
    }

    #pragma unroll
    for (int t = 0; t < TRn; ++t)
        #pragma unroll
        for (int off = 32; off > 0; off >>= 1)
            acc[t] += __shfl_down(acc[t], off, 64);
    __shared__ float red[4][TRn];
    int wave = tid >> 6, lane = tid & 63;
    if (lane == 0) {
        #pragma unroll
        for (int t = 0; t < TRn; ++t) red[wave][t] = acc[t];
    }
    __syncthreads();
    if (tid < TRn) {
        float s = rel_b[tid];
        #pragma unroll
        for (int w = 0; w < 4; ++w) s += red[w][tid];
        out_rel[(size_t)blk * TRn + tid] = s;
    }
}

extern "C" void kernel_launch(void* const* d_in, const int* in_sizes, int n_in,
                              void* d_out, int out_size, void* d_ws, size_t ws_size,
                              hipStream_t stream) {
    const float* hid       = (const float*)d_in[0];   // (B,L,H)
    const int*   ent_mask  = (const int*)d_in[1];     // (B,S,L)
    const int*   relations = (const int*)d_in[2];     // (B,R,2)
    const int*   rel_mask  = (const int*)d_in[3];     // (B,R,L)
    const int*   samp_mask = (const int*)d_in[4];     // (B,R)
    const float* size_emb  = (const float*)d_in[5];   // (100,E)
    const float* span_w    = (const float*)d_in[6];   // (2H+E, TE)
    const float* span_b    = (const float*)d_in[7];   // (TE,)
    const float* rel_w     = (const float*)d_in[8];   // (3H+2E, TR)
    const float* rel_b     = (const float*)d_in[9];   // (TR,)

    float* out = (float*)d_out;
    float* out_ent = out;                       // (B,S,TE)
    float* out_rel = out + Bn * Sn * TEn;       // (B,R,TR)

    char* ws = (char*)d_ws;
    float* entity = (float*)ws;                               // B*S*H
    float* relctx = entity + (size_t)Bn * Sn * Hn;            // B*R*H
    int*   entcnt = (int*)(relctx + (size_t)Bn * Rn * Hn);    // B*S

    span_kernel<<<Bn * (Sn + Rn), 192, 0, stream>>>(
        hid, ent_mask, rel_mask, samp_mask, size_emb, span_w, span_b,
        entity, relctx, entcnt, out_ent);

    rel_logit_kernel<<<Bn * Rn, 256, 0, stream>>>(
        entity, relctx, relations, entcnt, size_emb, rel_w, rel_b, out_rel);
}

// Round 6
// 24.617 us; speedup vs baseline: 7.6703x; 1.0652x over previous
//
#include <hip/hip_runtime.h>

#define Bn 4
#define Ln 512
#define Hn 768
#define Sn 100
#define Rn 100
#define En 128
#define TEn 8
#define TRn 6
#define NEGF (-1e20f)
#define W 8
#define NBLK (Ln / W)      // 64
#define H4 (Hn / 4)        // 192
#define E4 (En / 4)        // 32

__device__ __forceinline__ float4 fmax4(float4 a, float4 b) {
    return make_float4(fmaxf(a.x, b.x), fmaxf(a.y, b.y),
                       fmaxf(a.z, b.z), fmaxf(a.w, b.w));
}

// ---------------------------------------------------------------------------
// L1: bmax[b][j][:] = max over rows 8j..8j+7 of hid[b]. 256 blocks x 192 thr.
// ---------------------------------------------------------------------------
__global__ void __launch_bounds__(192)
blockmax_kernel(const float* __restrict__ hid, float* __restrict__ bmax) {
    int bj = blockIdx.x;                   // b*NBLK + j
    int b = bj / NBLK, j = bj % NBLK;
    int tid = threadIdx.x;
    const float4* src = (const float4*)(hid + ((size_t)b * Ln + j * W) * Hn);
    float4 m = src[tid];
    #pragma unroll
    for (int r = 1; r < W; ++r)
        m = fmax4(m, src[(size_t)r * H4 + tid]);
    ((float4*)(bmax + (size_t)bj * Hn))[tid] = m;
}

// wave-level contiguous-span scan: lane reads mask[8*lane .. 8*lane+7],
// returns {start, end} via shuffle reduce (valid in all lanes of the wave)
__device__ __forceinline__ void scan_span(const int* __restrict__ mask,
                                          int lane, int* start, int* end) {
    const int4* m4 = (const int4*)(mask + lane * 8);
    int4 a = m4[0], c = m4[1];
    int mm[8] = {a.x, a.y, a.z, a.w, c.x, c.y, c.z, c.w};
    int first = 0x7fffffff, last = -1;
    #pragma unroll
    for (int r = 0; r < 8; ++r) {
        if (mm[r] != 0) {
            int row = lane * 8 + r;
            first = min(first, row);
            last = max(last, row);
        }
    }
    #pragma unroll
    for (int off = 1; off < 64; off <<= 1) {
        first = min(first, __shfl_xor(first, off, 64));
        last = max(last, __shfl_xor(last, off, 64));
    }
    *start = first;
    *end = last + 1;
}

// masked max over rows [start,end) for this thread's 4 dims.
// hb4/bm4 are already offset by +tid; strides H4.
__device__ __forceinline__ float4 span_max(const float4* __restrict__ hb4,
                                           const float4* __restrict__ bm4,
                                           int start, int end) {
    float4 m = make_float4(NEGF, NEGF, NEGF, NEGF);
    int jstart = (start + 7) >> 3, jend = end >> 3;
    if (jstart >= jend) {                  // short span: raw rows only
        for (int r = start; r < end; ++r)
            m = fmax4(m, hb4[(size_t)r * H4]);
        return m;
    }
    int j = jstart;
    for (; j + 2 <= jend; j += 2)
        m = fmax4(m, fmax4(bm4[(size_t)j * H4], bm4[(size_t)(j + 1) * H4]));
    for (; j < jend; ++j)
        m = fmax4(m, bm4[(size_t)j * H4]);
    for (int r = start; r < jstart * W; ++r)
        m = fmax4(m, hb4[(size_t)r * H4]);
    for (int r = jend * W; r < end; ++r)
        m = fmax4(m, hb4[(size_t)r * H4]);
    return m;
}

// ---------------------------------------------------------------------------
// L2: 800 blocks x 256 threads.
//   blocks [0, B*S): entity logits (span max from bmax + fused logit)
//   blocks [B*S, B*S+B*R): relation logits (recompute e0/e1/relctx locally)
// ---------------------------------------------------------------------------
__global__ void __launch_bounds__(256)
logits_kernel(const float* __restrict__ hid,
              const int* __restrict__ ent_mask,
              const int* __restrict__ rel_mask,
              const int* __restrict__ samp_mask,
              const int* __restrict__ relations,
              const float* __restrict__ size_emb,
              const float* __restrict__ span_w,
              const float* __restrict__ span_b,
              const float* __restrict__ rel_w,
              const float* __restrict__ rel_b,
              const float* __restrict__ bmax,
              float* __restrict__ out_ent,
              float* __restrict__ out_rel) {
    int blk = blockIdx.x;
    int tid = threadIdx.x;
    int lane = tid & 63, wv = tid >> 6;

    __shared__ int se[3][2];
    __shared__ float red[4][TEn];

    if (blk < Bn * Sn) {
        // ================= entity logit block =================
        int b = blk / Sn;
        if (wv == 0) {
            int s0, e0;
            scan_span(ent_mask + (size_t)blk * Ln, lane, &s0, &e0);
            if (lane == 0) { se[0][0] = s0; se[0][1] = e0; }
        }
        __syncthreads();
        int start = se[0][0], end = se[0][1];
        int cnt = end - start;

        float acc[TEn];
        #pragma unroll
        for (int t = 0; t < TEn; ++t) acc[t] = 0.0f;

        if (tid < H4) {
            const float4* hb4 = (const float4*)(hid + (size_t)b * Ln * Hn) + tid;
            const float4* bm4 = (const float4*)(bmax + (size_t)b * NBLK * Hn) + tid;
            float4 m = span_max(hb4, bm4, start, end);

            const float* vv = &m.x;            // entity dims 4*tid..4*tid+3
            #pragma unroll
            for (int j = 0; j < 4; ++j) {
                const float4* w4 = (const float4*)(span_w + (size_t)(4 * tid + j) * TEn);
                float4 wa = w4[0], wb = w4[1];
                acc[0] += vv[j] * wa.x; acc[1] += vv[j] * wa.y;
                acc[2] += vv[j] * wa.z; acc[3] += vv[j] * wa.w;
                acc[4] += vv[j] * wb.x; acc[5] += vv[j] * wb.y;
                acc[6] += vv[j] * wb.z; acc[7] += vv[j] * wb.w;
            }
            float4 c = ((const float4*)(hid + (size_t)b * Ln * Hn))[tid]; // ctx row 0
            const float* cc = &c.x;
            #pragma unroll
            for (int j = 0; j < 4; ++j) {
                const float4* w4 = (const float4*)(span_w + (size_t)(Hn + 4 * tid + j) * TEn);
                float4 wa = w4[0], wb = w4[1];
                acc[0] += cc[j] * wa.x; acc[1] += cc[j] * wa.y;
                acc[2] += cc[j] * wa.z; acc[3] += cc[j] * wa.w;
                acc[4] += cc[j] * wb.x; acc[5] += cc[j] * wb.y;
                acc[6] += cc[j] * wb.z; acc[7] += cc[j] * wb.w;
            }
        } else if (tid >= 192 && tid < 192 + E4) {
            // 4th wave handles the size-embedding segment
            int u = tid - 192;
            float4 sv = ((const float4*)(size_emb + (size_t)cnt * En))[u];
            const float* ss = &sv.x;
            #pragma unroll
            for (int j = 0; j < 4; ++j) {
                const float4* w4 = (const float4*)(span_w + (size_t)(2 * Hn + 4 * u + j) * TEn);
                float4 wa = w4[0], wb = w4[1];
                acc[0] += ss[j] * wa.x; acc[1] += ss[j] * wa.y;
                acc[2] += ss[j] * wa.z; acc[3] += ss[j] * wa.w;
                acc[4] += ss[j] * wb.x; acc[5] += ss[j] * wb.y;
                acc[6] += ss[j] * wb.z; acc[7] += ss[j] * wb.w;
            }
        }

        #pragma unroll
        for (int t = 0; t < TEn; ++t)
            #pragma unroll
            for (int off = 32; off > 0; off >>= 1)
                acc[t] += __shfl_down(acc[t], off, 64);
        if (lane == 0) {
            #pragma unroll
            for (int t = 0; t < TEn; ++t) red[wv][t] = acc[t];
        }
        __syncthreads();
        if (tid < TEn) {
            float s = span_b[tid];
            #pragma unroll
            for (int w = 0; w < 4; ++w) s += red[w][tid];
            out_ent[(size_t)blk * TEn + tid] = s;
        }
    } else {
        // ================= relation logit block =================
        int rblk = blk - Bn * Sn;              // b*R + r
        int b = rblk / Rn;
        int a0 = relations[rblk * 2 + 0];
        int a1 = relations[rblk * 2 + 1];
        bool samp = (samp_mask[rblk] == 1);

        if (wv == 0) {
            int s0, e0;
            scan_span(ent_mask + ((size_t)b * Sn + a0) * Ln, lane, &s0, &e0);
            if (lane == 0) { se[0][0] = s0; se[0][1] = e0; }
        } else if (wv == 1) {
            int s1, e1;
            scan_span(ent_mask + ((size_t)b * Sn + a1) * Ln, lane, &s1, &e1);
            if (lane == 0) { se[1][0] = s1; se[1][1] = e1; }
        } else if (wv == 2 && !samp) {
            int s2, e2;
            scan_span(rel_mask + (size_t)rblk * Ln, lane, &s2, &e2);
            if (lane == 0) { se[2][0] = s2; se[2][1] = e2; }
        }
        __syncthreads();
        int cnt0 = se[0][1] - se[0][0];
        int cnt1 = se[1][1] - se[1][0];

        float acc[TRn];
        #pragma unroll
        for (int t = 0; t < TRn; ++t) acc[t] = 0.0f;

        if (tid < H4) {
            const float4* hb4 = (const float4*)(hid + (size_t)b * Ln * Hn) + tid;
            const float4* bm4 = (const float4*)(bmax + (size_t)b * NBLK * Hn) + tid;

            float4 ve0 = span_max(hb4, bm4, se[0][0], se[0][1]);
            float4 ve1 = span_max(hb4, bm4, se[1][0], se[1][1]);
            float4 vc = samp ? make_float4(0.f, 0.f, 0.f, 0.f)
                             : span_max(hb4, bm4, se[2][0], se[2][1]);

            // dot: segment bases k4 = {tid (ctx), H4+tid (e0), 2H4+tid (e1)}
            const float* vp;
            #pragma unroll
            for (int seg = 0; seg < 3; ++seg) {
                float4 v = (seg == 0) ? vc : (seg == 1) ? ve0 : ve1;
                vp = &v.x;
                int k4 = seg * H4 + tid;
                #pragma unroll
                for (int j = 0; j < 4; ++j) {
                    const float2* wr = (const float2*)(rel_w + (size_t)(4 * k4 + j) * TRn);
                    float2 w0 = wr[0], w1 = wr[1], w2 = wr[2];
                    acc[0] += vp[j] * w0.x; acc[1] += vp[j] * w0.y;
                    acc[2] += vp[j] * w1.x; acc[3] += vp[j] * w1.y;
                    acc[4] += vp[j] * w2.x; acc[5] += vp[j] * w2.y;
                }
            }
        } else if (tid >= 192) {
            // 4th wave: size segments s0 (u<32) and s1 (u>=32)
            int u = tid - 192;
            int k4, srow;
            if (u < E4) { srow = cnt0; k4 = 3 * H4 + u; }
            else        { srow = cnt1; k4 = 3 * H4 + E4 + (u - E4); }
            int uu = (u < E4) ? u : u - E4;
            float4 sv = ((const float4*)(size_emb + (size_t)srow * En))[uu];
            const float* sp = &sv.x;
            #pragma unroll
            for (int j = 0; j < 4; ++j) {
                const float2* wr = (const float2*)(rel_w + (size_t)(4 * k4 + j) * TRn);
                float2 w0 = wr[0], w1 = wr[1], w2 = wr[2];
                acc[0] += sp[j] * w0.x; acc[1] += sp[j] * w0.y;
                acc[2] += sp[j] * w1.x; acc[3] += sp[j] * w1.y;
                acc[4] += sp[j] * w2.x; acc[5] += sp[j] * w2.y;
            }
        }

        #pragma unroll
        for (int t = 0; t < TRn; ++t)
            #pragma unroll
            for (int off = 32; off > 0; off >>= 1)
                acc[t] += __shfl_down(acc[t], off, 64);
        if (lane == 0) {
            #pragma unroll
            for (int t = 0; t < TRn; ++t) red[wv][t] = acc[t];
        }
        __syncthreads();
        if (tid < TRn) {
            float s = rel_b[tid];
            #pragma unroll
            for (int w = 0; w < 4; ++w) s += red[w][tid];
            out_rel[(size_t)rblk * TRn + tid] = s;
        }
    }
}

extern "C" void kernel_launch(void* const* d_in, const int* in_sizes, int n_in,
                              void* d_out, int out_size, void* d_ws, size_t ws_size,
                              hipStream_t stream) {
    const float* hid       = (const float*)d_in[0];   // (B,L,H)
    const int*   ent_mask  = (const int*)d_in[1];     // (B,S,L)
    const int*   relations = (const int*)d_in[2];     // (B,R,2)
    const int*   rel_mask  = (const int*)d_in[3];     // (B,R,L)
    const int*   samp_mask = (const int*)d_in[4];     // (B,R)
    const float* size_emb  = (const float*)d_in[5];   // (100,E)
    const float* span_w    = (const float*)d_in[6];   // (2H+E, TE)
    const float* span_b    = (const float*)d_in[7];   // (TE,)
    const float* rel_w     = (const float*)d_in[8];   // (3H+2E, TR)
    const float* rel_b     = (const float*)d_in[9];   // (TR,)

    float* out = (float*)d_out;
    float* out_ent = out;                       // (B,S,TE)
    float* out_rel = out + Bn * Sn * TEn;       // (B,R,TR)

    float* bmax = (float*)d_ws;                 // B*NBLK*H floats (~786 KB)

    blockmax_kernel<<<Bn * NBLK, 192, 0, stream>>>(hid, bmax);

    logits_kernel<<<Bn * (Sn + Rn), 256, 0, stream>>>(
        hid, ent_mask, rel_mask, samp_mask, relations, size_emb,
        span_w, span_b, rel_w, rel_b, bmax, out_ent, out_rel);
}

// Round 7
// 22.250 us; speedup vs baseline: 8.4865x; 1.1064x over previous
//
#include <hip/hip_runtime.h>

#define Bn 4
#define Ln 512
#define Hn 768
#define Sn 100
#define Rn 100
#define En 128
#define TEn 8
#define TRn 6
#define NEGF (-1e20f)
#define W 8
#define NBLK (Ln / W)      // 64
#define H4 (Hn / 4)        // 192
#define E4 (En / 4)        // 32
#define NTHR 640           // 10 waves

__device__ __forceinline__ float4 fmax4(float4 a, float4 b) {
    return make_float4(fmaxf(a.x, b.x), fmaxf(a.y, b.y),
                       fmaxf(a.z, b.z), fmaxf(a.w, b.w));
}

// ---------------------------------------------------------------------------
// L1: bmax[b][j][:] = max over rows 8j..8j+7 of hid[b]. 256 blocks x 192 thr.
// ---------------------------------------------------------------------------
__global__ void __launch_bounds__(192)
blockmax_kernel(const float* __restrict__ hid, float* __restrict__ bmax) {
    int bj = blockIdx.x;                   // b*NBLK + j
    int b = bj / NBLK, j = bj % NBLK;
    int tid = threadIdx.x;
    const float4* src = (const float4*)(hid + ((size_t)b * Ln + j * W) * Hn);
    float4 m0 = src[tid];
    float4 m1 = src[(size_t)H4 + tid];
    #pragma unroll
    for (int r = 2; r < W; r += 2) {
        m0 = fmax4(m0, src[(size_t)r * H4 + tid]);
        m1 = fmax4(m1, src[(size_t)(r + 1) * H4 + tid]);
    }
    ((float4*)(bmax + (size_t)bj * Hn))[tid] = fmax4(m0, m1);
}

// wave-level contiguous-span scan: lane reads mask[8*lane .. 8*lane+7],
// returns {start, end} via shuffle reduce (valid in all lanes)
__device__ __forceinline__ void scan_span(const int* __restrict__ mask,
                                          int lane, int* start, int* end) {
    const int4* m4 = (const int4*)(mask + lane * 8);
    int4 a = m4[0], c = m4[1];
    int mm[8] = {a.x, a.y, a.z, a.w, c.x, c.y, c.z, c.w};
    int first = 0x7fffffff, last = -1;
    #pragma unroll
    for (int r = 0; r < 8; ++r) {
        if (mm[r] != 0) {
            int row = lane * 8 + r;
            first = min(first, row);
            last = max(last, row);
        }
    }
    #pragma unroll
    for (int off = 1; off < 64; off <<= 1) {
        first = min(first, __shfl_xor(first, off, 64));
        last = max(last, __shfl_xor(last, off, 64));
    }
    *start = first;
    *end = last + 1;
}

// masked max over rows [start,end) for this thread's 4 dims; 2 indep accs.
__device__ __forceinline__ float4 span_max(const float4* __restrict__ hb4,
                                           const float4* __restrict__ bm4,
                                           int start, int end) {
    float4 m0 = make_float4(NEGF, NEGF, NEGF, NEGF);
    float4 m1 = m0;
    int jstart = (start + 7) >> 3, jend = end >> 3;
    if (jstart >= jend) {                  // short span: raw rows only
        int r = start;
        for (; r + 2 <= end; r += 2) {
            m0 = fmax4(m0, hb4[(size_t)r * H4]);
            m1 = fmax4(m1, hb4[(size_t)(r + 1) * H4]);
        }
        if (r < end) m0 = fmax4(m0, hb4[(size_t)r * H4]);
        return fmax4(m0, m1);
    }
    int j = jstart;
    for (; j + 4 <= jend; j += 4) {
        m0 = fmax4(m0, fmax4(bm4[(size_t)j * H4], bm4[(size_t)(j + 1) * H4]));
        m1 = fmax4(m1, fmax4(bm4[(size_t)(j + 2) * H4], bm4[(size_t)(j + 3) * H4]));
    }
    for (; j < jend; ++j) m0 = fmax4(m0, bm4[(size_t)j * H4]);
    int he = jstart * W;
    int r = start;
    for (; r + 2 <= he; r += 2) {
        m0 = fmax4(m0, hb4[(size_t)r * H4]);
        m1 = fmax4(m1, hb4[(size_t)(r + 1) * H4]);
    }
    if (r < he) m0 = fmax4(m0, hb4[(size_t)r * H4]);
    r = jend * W;
    for (; r + 2 <= end; r += 2) {
        m0 = fmax4(m0, hb4[(size_t)r * H4]);
        m1 = fmax4(m1, hb4[(size_t)(r + 1) * H4]);
    }
    if (r < end) m0 = fmax4(m0, hb4[(size_t)r * H4]);
    return fmax4(m0, m1);
}

// dot of this thread's float4 v against NT-wide weight rows [4*row..4*row+3]
template <int NT>
__device__ __forceinline__ void dot4(const float4 v, const float* __restrict__ wbase,
                                     int row, float* acc) {
    const float* vp = &v.x;
    #pragma unroll
    for (int j = 0; j < 4; ++j) {
        const float* wr = wbase + (size_t)(4 * row + j) * NT;
        #pragma unroll
        for (int t = 0; t < NT; ++t) acc[t] += vp[j] * wr[t];
    }
}

// ---------------------------------------------------------------------------
// L2: 800 blocks x 640 threads. Segment-parallel:
//  entity blk: [0,192) entity-seg | [192,384) ctx-seg | [384,416) size-seg
//  rel blk:    [0,192) relctx | [192,384) e0 | [384,576) e1 |
//              [576,608) s0 | [608,640) s1
// ---------------------------------------------------------------------------
__global__ void __launch_bounds__(NTHR)
logits_kernel(const float* __restrict__ hid,
              const int* __restrict__ ent_mask,
              const int* __restrict__ rel_mask,
              const int* __restrict__ samp_mask,
              const int* __restrict__ relations,
              const float* __restrict__ size_emb,
              const float* __restrict__ span_w,
              const float* __restrict__ span_b,
              const float* __restrict__ rel_w,
              const float* __restrict__ rel_b,
              const float* __restrict__ bmax,
              float* __restrict__ out_ent,
              float* __restrict__ out_rel) {
    int blk = blockIdx.x;
    int tid = threadIdx.x;
    int lane = tid & 63, wv = tid >> 6;

    __shared__ int se[3][2];
    __shared__ float red[10][TEn];

    float acc[TEn];
    #pragma unroll
    for (int t = 0; t < TEn; ++t) acc[t] = 0.0f;

    if (blk < Bn * Sn) {
        // ================= entity logit block =================
        int b = blk / Sn;
        if (wv == 0) {
            int s0, e0;
            scan_span(ent_mask + (size_t)blk * Ln, lane, &s0, &e0);
            if (lane == 0) { se[0][0] = s0; se[0][1] = e0; }
        }
        __syncthreads();
        int start = se[0][0], end = se[0][1];
        int cnt = end - start;

        const float4* hb4 = (const float4*)(hid + (size_t)b * Ln * Hn);
        if (tid < 192) {
            const float4* bm4 = (const float4*)(bmax + (size_t)b * NBLK * Hn) + tid;
            float4 m = span_max(hb4 + tid, bm4, start, end);
            dot4<TEn>(m, span_w, tid, acc);
        } else if (tid < 384) {
            int u = tid - 192;
            dot4<TEn>(hb4[u], span_w, H4 + u, acc);           // ctx = row 0
        } else if (tid < 384 + E4) {
            int u = tid - 384;
            float4 sv = ((const float4*)(size_emb + (size_t)cnt * En))[u];
            dot4<TEn>(sv, span_w, 2 * H4 + u, acc);
        }

        #pragma unroll
        for (int t = 0; t < TEn; ++t)
            #pragma unroll
            for (int off = 32; off > 0; off >>= 1)
                acc[t] += __shfl_down(acc[t], off, 64);
        if (lane == 0) {
            #pragma unroll
            for (int t = 0; t < TEn; ++t) red[wv][t] = acc[t];
        }
        __syncthreads();
        if (tid < TEn) {
            float s = span_b[tid];
            #pragma unroll
            for (int w = 0; w < 10; ++w) s += red[w][tid];
            out_ent[(size_t)blk * TEn + tid] = s;
        }
    } else {
        // ================= relation logit block =================
        int rblk = blk - Bn * Sn;              // b*R + r
        int b = rblk / Rn;
        int a0 = relations[rblk * 2 + 0];
        int a1 = relations[rblk * 2 + 1];
        bool samp = (samp_mask[rblk] == 1);

        if (wv == 0) {
            if (!samp) {
                int s0, e0;
                scan_span(rel_mask + (size_t)rblk * Ln, lane, &s0, &e0);
                if (lane == 0) { se[0][0] = s0; se[0][1] = e0; }
            }
        } else if (wv == 1) {
            int s1, e1;
            scan_span(ent_mask + ((size_t)b * Sn + a0) * Ln, lane, &s1, &e1);
            if (lane == 0) { se[1][0] = s1; se[1][1] = e1; }
        } else if (wv == 2) {
            int s2, e2;
            scan_span(ent_mask + ((size_t)b * Sn + a1) * Ln, lane, &s2, &e2);
            if (lane == 0) { se[2][0] = s2; se[2][1] = e2; }
        }
        __syncthreads();
        int cnt0 = se[1][1] - se[1][0];
        int cnt1 = se[2][1] - se[2][0];

        const float4* hb4 = (const float4*)(hid + (size_t)b * Ln * Hn);
        const float4* bm4 = (const float4*)(bmax + (size_t)b * NBLK * Hn);
        if (tid < 192) {
            if (!samp) {
                float4 m = span_max(hb4 + tid, bm4 + tid, se[0][0], se[0][1]);
                dot4<TRn>(m, rel_w, tid, acc);
            }
        } else if (tid < 384) {
            int u = tid - 192;
            float4 m = span_max(hb4 + u, bm4 + u, se[1][0], se[1][1]);
            dot4<TRn>(m, rel_w, H4 + u, acc);
        } else if (tid < 576) {
            int u = tid - 384;
            float4 m = span_max(hb4 + u, bm4 + u, se[2][0], se[2][1]);
            dot4<TRn>(m, rel_w, 2 * H4 + u, acc);
        } else if (tid < 576 + E4) {
            int u = tid - 576;
            float4 sv = ((const float4*)(size_emb + (size_t)cnt0 * En))[u];
            dot4<TRn>(sv, rel_w, 3 * H4 + u, acc);
        } else {
            int u = tid - 576 - E4;
            float4 sv = ((const float4*)(size_emb + (size_t)cnt1 * En))[u];
            dot4<TRn>(sv, rel_w, 3 * H4 + E4 + u, acc);
        }

        #pragma unroll
        for (int t = 0; t < TRn; ++t)
            #pragma unroll
            for (int off = 32; off > 0; off >>= 1)
                acc[t] += __shfl_down(acc[t], off, 64);
        if (lane == 0) {
            #pragma unroll
            for (int t = 0; t < TRn; ++t) red[wv][t] = acc[t];
        }
        __syncthreads();
        if (tid < TRn) {
            float s = rel_b[tid];
            #pragma unroll
            for (int w = 0; w < 10; ++w) s += red[w][tid];
            out_rel[(size_t)rblk * TRn + tid] = s;
        }
    }
}

extern "C" void kernel_launch(void* const* d_in, const int* in_sizes, int n_in,
                              void* d_out, int out_size, void* d_ws, size_t ws_size,
                              hipStream_t stream) {
    const float* hid       = (const float*)d_in[0];   // (B,L,H)
    const int*   ent_mask  = (const int*)d_in[1];     // (B,S,L)
    const int*   relations = (const int*)d_in[2];     // (B,R,2)
    const int*   rel_mask  = (const int*)d_in[3];     // (B,R,L)
    const int*   samp_mask = (const int*)d_in[4];     // (B,R)
    const float* size_emb  = (const float*)d_in[5];   // (100,E)
    const float* span_w    = (const float*)d_in[6];   // (2H+E, TE)
    const float* span_b    = (const float*)d_in[7];   // (TE,)
    const float* rel_w     = (const float*)d_in[8];   // (3H+2E, TR)
    const float* rel_b     = (const float*)d_in[9];   // (TR,)

    float* out = (float*)d_out;
    float* out_ent = out;                       // (B,S,TE)
    float* out_rel = out + Bn * Sn * TEn;       // (B,R,TR)

    float* bmax = (float*)d_ws;                 // B*NBLK*H floats (~786 KB)

    blockmax_kernel<<<Bn * NBLK, 192, 0, stream>>>(hid, bmax);

    logits_kernel<<<Bn * (Sn + Rn), NTHR, 0, stream>>>(
        hid, ent_mask, rel_mask, samp_mask, relations, size_emb,
        span_w, span_b, rel_w, rel_b, bmax, out_ent, out_rel);
}